// Round 10
// baseline (457.867 us; speedup 1.0000x reference)
//
#include <hip/hip_runtime.h>
#include <hip/hip_bf16.h>
#include <stdint.h>

// ---------------------------------------------------------------------------
// PairRepulsionSwitch: per-edge ZBL + r^-12 repulsion, quarter-summed to both
// endpoint nodes.
//
// R1-R8 history: global atomics rate-limited (655us) -> binning (373) ->
// LDS sort (327) -> node-range multipass LDS accum (273) -> compaction (255).
// R9: split energy/accum -> accum 78.5us, energy ~70us, ~90us fixed harness
//     overhead identified (kernel-sum + 90 == dur_us across all rounds).
// R10: (a) species trick: one-hot over N_ELEM=10 elements -> per-node uint8
//      species (100KB table, L1-friendly 1B gathers) + 100-entry per-pair
//      LDS table {KE*Zi*Zj, (Zi^.23+Zj^.23)/ac} (transcendental prep for 100
//      pairs, not 100K nodes). (b) energy fused with packing: 8B records
//      {src | dst<<nb | q_top_bits<<2nb} -> accum reads 8B/edge (was 12).
//      (c) accum 8 edges/iter (4 independent uint4 loads), records padded to
//      S*EPB so the K-loop is branch-free. S%8==0 XCD invariant kept.
// ---------------------------------------------------------------------------

#define KE_CONST 14.3996454784255f
constexpr float INV_AC = 1.0f / (0.88534f * 0.52917721092f);

#define NR 12800             // nodes per range (50 KB accumulator, 3 blk/CU)
#define PT_MAX 256           // max n_elem^2 pair-table entries (2 KB LDS)

// ---------------------------------------------------------------- shared math
// c.x = KE*Zi*Zj*SCALE, c.y = (Zi^0.23 + Zj^0.23) * INV_AC
__device__ __forceinline__ float edge_energy_pt(float len, float2 c,
                                                float inv_rmax) {
    float r = fmaxf(len, 0.2f);                 // R_MIN clamp
    float inv_r = 1.0f / r;

    float u = fmaxf(1.0f - r * inv_rmax, 0.0f);
    float u2 = u * u;
    float pc = u2 * u2 * u2;                    // (1-x)^6

    float x = r * c.y;
    float phi = 0.1818f   * __expf(-3.2f    * x)
              + 0.5099f   * __expf(-0.9423f * x)
              + 0.2802f   * __expf(-0.4029f * x)
              + 0.02817f  * __expf(-0.2016f * x);
    float v_zbl = c.x * phi * inv_r * pc;

    float ir2 = inv_r * inv_r;
    float ir4 = ir2 * ir2;
    float ir12 = ir4 * ir4 * ir4;
    float t = fminf(fmaxf((1.5f - r) * 5.0f, 0.0f), 1.0f);
    float sm = t * t * (3.0f - 2.0f * t);
    float v_r12 = 1e-4f * ir12 * pc * sm;

    return 0.25f * (v_zbl + v_r12);
}

__device__ __forceinline__ float edge_energy(float len, float2 zi, float2 zj,
                                             float inv_rmax) {
    float2 c = make_float2(KE_CONST * zi.x * zj.x, (zi.y + zj.y) * INV_AC);
    return edge_energy_pt(len, c, inv_rmax);
}

__device__ __forceinline__ uint16_t f32_to_bf16_rne(float v) {
    uint32_t u = __float_as_uint(v);
    u += 0x7FFFu + ((u >> 16) & 1u);
    return (uint16_t)(u >> 16);
}

// ---------------------------------------------------------------- prep
__global__ void species_kernel(const float* __restrict__ node_attrs,
                               uint8_t* __restrict__ spec,
                               int n_nodes, int n_elem) {
    int i = blockIdx.x * blockDim.x + threadIdx.x;
    if (i >= n_nodes) return;
    float v = 0.0f;
    for (int k = 0; k < n_elem; ++k)
        v += node_attrs[i * n_elem + k] * (float)k;
    spec[i] = (uint8_t)(v + 0.5f);
}

__global__ void pair_kernel(const float* __restrict__ atomic_numbers,
                            float2* __restrict__ ptab, int n_elem) {
    int idx = threadIdx.x;
    int n2 = n_elem * n_elem;
    if (idx >= n2) return;
    int i = idx / n_elem, j = idx % n_elem;
    float Zi = atomic_numbers[i], Zj = atomic_numbers[j];
    ptab[idx] = make_float2(KE_CONST * Zi * Zj,
                            (powf(Zi, 0.23f) + powf(Zj, 0.23f)) * INV_AC);
}

__global__ void prep_nodes_kernel(const float* __restrict__ node_attrs,
                                  const float* __restrict__ atomic_numbers,
                                  float2* __restrict__ ztab,
                                  int n_nodes, int n_elem) {
    int i = blockIdx.x * blockDim.x + threadIdx.x;
    if (i >= n_nodes) return;
    float z = 0.0f;
    for (int k = 0; k < n_elem; ++k)
        z += node_attrs[i * n_elem + k] * atomic_numbers[k];
    ztab[i] = make_float2(z, powf(z, 0.23f));
}

// ------------------------------------------------- energy + pack (8B records)
__global__ __launch_bounds__(256) void energy_pack_kernel(
    const float* __restrict__ lengths,
    const int* __restrict__ src, const int* __restrict__ dst,
    const uint8_t* __restrict__ spec,
    const float2* __restrict__ ptab_g,
    const float* __restrict__ rmax_ptr,
    unsigned long long* __restrict__ recs,
    int n_edges, int total, int n_elem, int nb, int qshift, int vec_ok) {
    __shared__ float2 pt[PT_MAX];
    int tid = threadIdx.x;
    int n2 = n_elem * n_elem;
    for (int i = tid; i < n2; i += 256) pt[i] = ptab_g[i];
    __syncthreads();

    const float inv_rmax = 1.0f / rmax_ptr[0];
    int t = blockIdx.x * blockDim.x + tid;
    int base = t * 4;
    if (base >= total) return;
    int nb2 = 2 * nb;

    if (vec_ok && base + 3 < n_edges) {
        float4 L  = *reinterpret_cast<const float4*>(lengths + base);
        int4   S4 = *reinterpret_cast<const int4*>(src + base);
        int4   D4 = *reinterpret_cast<const int4*>(dst + base);
        int sv[4] = {S4.x, S4.y, S4.z, S4.w};
        int dv[4] = {D4.x, D4.y, D4.z, D4.w};
        float lv[4] = {L.x, L.y, L.z, L.w};
        int spi[4], spj[4];
#pragma unroll
        for (int k = 0; k < 4; ++k) {
            spi[k] = spec[sv[k]];
            spj[k] = spec[dv[k]];
        }
        unsigned long long rv[4];
#pragma unroll
        for (int k = 0; k < 4; ++k) {
            float2 c = pt[spi[k] * n_elem + spj[k]];
            float q = edge_energy_pt(lv[k], c, inv_rmax);
            uint32_t qu = __float_as_uint(q) >> qshift;
            rv[k] = (unsigned long long)(unsigned)sv[k]
                  | ((unsigned long long)(unsigned)dv[k] << nb)
                  | ((unsigned long long)qu << nb2);
        }
        uint4* out = reinterpret_cast<uint4*>(recs + base);
        out[0] = make_uint4((uint32_t)rv[0], (uint32_t)(rv[0] >> 32),
                            (uint32_t)rv[1], (uint32_t)(rv[1] >> 32));
        out[1] = make_uint4((uint32_t)rv[2], (uint32_t)(rv[2] >> 32),
                            (uint32_t)rv[3], (uint32_t)(rv[3] >> 32));
    } else {
        for (int k = 0; k < 4; ++k) {
            int e = base + k;
            if (e >= total) break;
            unsigned long long rec = 0ull;
            if (e < n_edges) {
                int si = src[e], di = dst[e];
                float2 c = pt[spec[si] * n_elem + spec[di]];
                float q = edge_energy_pt(lengths[e], c, inv_rmax);
                uint32_t qu = __float_as_uint(q) >> qshift;
                rec = (unsigned long long)(unsigned)si
                    | ((unsigned long long)(unsigned)di << nb)
                    | ((unsigned long long)qu << (2 * nb));
            }
            recs[e] = rec;
        }
    }
}

// --------------------------------------------------------------- accumulate
__global__ __launch_bounds__(512) void accum_kernel(
    const unsigned long long* __restrict__ recs,
    uint16_t* __restrict__ partial,      // S rows of npad bf16
    int S, int EPB, int npad, int nb, int qshift) {
    __shared__ float acc[NR];
    int tid = threadIdx.x;
    for (int i = tid; i < NR; i += 512) acc[i] = 0.0f;
    __syncthreads();

    int s = blockIdx.x % S;              // S%8==0: same-s blocks -> same XCD
    int p = blockIdx.x / S;
    const unsigned base = (unsigned)p * NR;
    const unsigned nmask = (1u << nb) - 1u;
    const int nb2 = 2 * nb;

    int e0 = s * EPB;
    int e1 = e0 + EPB;                   // records padded: always full

    for (int off = e0 + tid * 8; off < e1; off += 512 * 8) {
        uint4 r0 = *reinterpret_cast<const uint4*>(recs + off);
        uint4 r1 = *reinterpret_cast<const uint4*>(recs + off + 2);
        uint4 r2 = *reinterpret_cast<const uint4*>(recs + off + 4);
        uint4 r3 = *reinterpret_cast<const uint4*>(recs + off + 6);
        uint4 rr[4] = {r0, r1, r2, r3};
#pragma unroll
        for (int k = 0; k < 4; ++k) {
            unsigned long long ra =
                (unsigned long long)rr[k].x | ((unsigned long long)rr[k].y << 32);
            unsigned long long rb =
                (unsigned long long)rr[k].z | ((unsigned long long)rr[k].w << 32);
#pragma unroll
            for (int h = 0; h < 2; ++h) {
                unsigned long long rec = h ? rb : ra;
                unsigned sn = (unsigned)rec & nmask;
                unsigned dn = (unsigned)(rec >> nb) & nmask;
                float q = __uint_as_float((uint32_t)(rec >> nb2) << qshift);
                unsigned a = sn - base;
                if (a < NR) atomicAdd(&acc[a], q);
                unsigned b = dn - base;
                if (b < NR) atomicAdd(&acc[b], q);
            }
        }
    }
    __syncthreads();

    uint16_t* __restrict__ row = partial + (size_t)s * npad + base;
    for (int i = tid; i < NR; i += 512)
        row[i] = f32_to_bf16_rne(acc[i]);
}

__global__ void combine_kernel(const uint16_t* __restrict__ partial,
                               float* __restrict__ out,
                               int n_nodes, int S, int npad) {
    int i = blockIdx.x * blockDim.x + threadIdx.x;
    if (i >= n_nodes) return;
    float t = 0.0f;
    for (int s = 0; s < S; ++s) {
        uint32_t h = partial[(size_t)s * npad + i];
        t += __uint_as_float(h << 16);
    }
    out[i] = t;
}

// ----------------------------------------------------------- fallback (R2)
__global__ void zero_out_kernel(float* __restrict__ out, int n) {
    int i = blockIdx.x * blockDim.x + threadIdx.x;
    if (i < n) out[i] = 0.0f;
}

__global__ __launch_bounds__(256) void edge_kernel_atomic(
    const float* __restrict__ lengths,
    const int* __restrict__ src_idx,
    const int* __restrict__ dst_idx,
    const float2* __restrict__ ztab,
    const float* __restrict__ rmax_ptr,
    float* __restrict__ out,
    int n_edges) {
    const float inv_rmax = 1.0f / rmax_ptr[0];
    int t = blockIdx.x * blockDim.x + threadIdx.x;
    int base = t * 4;
    if (base + 3 < n_edges) {
        float4 L = *reinterpret_cast<const float4*>(lengths + base);
        int4 S = *reinterpret_cast<const int4*>(src_idx + base);
        int4 D = *reinterpret_cast<const int4*>(dst_idx + base);
        float l[4] = {L.x, L.y, L.z, L.w};
        int s[4] = {S.x, S.y, S.z, S.w};
        int d[4] = {D.x, D.y, D.z, D.w};
        float2 zs[4], zd[4];
#pragma unroll
        for (int k = 0; k < 4; ++k) { zs[k] = ztab[s[k]]; zd[k] = ztab[d[k]]; }
#pragma unroll
        for (int k = 0; k < 4; ++k) {
            float q = edge_energy(l[k], zs[k], zd[k], inv_rmax);
            unsafeAtomicAdd(&out[s[k]], q);
            unsafeAtomicAdd(&out[d[k]], q);
        }
    } else if (base < n_edges) {
        for (int e = base; e < n_edges; ++e) {
            int si = src_idx[e], di = dst_idx[e];
            float q = edge_energy(lengths[e], ztab[si], ztab[di], inv_rmax);
            unsafeAtomicAdd(&out[si], q);
            unsafeAtomicAdd(&out[di], q);
        }
    }
}

// ---------------------------------------------------------------- launcher
extern "C" void kernel_launch(void* const* d_in, const int* in_sizes, int n_in,
                              void* d_out, int out_size, void* d_ws, size_t ws_size,
                              hipStream_t stream) {
    const float* lengths        = (const float*)d_in[0];
    const float* node_attrs     = (const float*)d_in[1];
    const int*   edge_index     = (const int*)d_in[2];
    const float* atomic_numbers = (const float*)d_in[3];
    const float* rmax_ptr       = (const float*)d_in[4];

    int n_edges = in_sizes[0];
    int n_elem  = in_sizes[3];
    int n_nodes = out_size;
    float* out = (float*)d_out;

    const int* src = edge_index;
    const int* dst = edge_index + n_edges;

    int P    = (n_nodes + NR - 1) / NR;
    int npad = P * NR;
    int vec_ok = ((n_edges & 3) == 0) ? 1 : 0;

    // record packing: nb bits per node id, q gets 64-2nb (<=32) bits
    int nb = 1;
    while ((1u << nb) < (unsigned)n_nodes) nb++;
    int qb = 64 - 2 * nb;
    if (qb > 32) qb = 32;
    int qshift = 32 - qb;
    bool pack_ok = (2 * nb + 16 <= 64) && (n_elem * n_elem <= PT_MAX);

    // S: multiple of 8 (XCD invariant), grid P*S <= 768 (3 blk/CU, 50KB LDS)
    int S = (768 / P) & ~7;
    if (S < 8) S = 8;
    size_t rec_off = 0, part_off = 0, ptab_off = 0, spec_off = 0, need = 0;
    int EPB = 0, TOTAL = 0;
    for (; S >= 8; S -= 8) {
        EPB = (((n_edges + S - 1) / S) + 4095) & ~4095;   // mult of 4096
        TOTAL = S * EPB;
        rec_off  = 0;
        part_off = ((size_t)TOTAL * 8 + 255) & ~(size_t)255;
        ptab_off = (part_off + (size_t)S * npad * 2 + 255) & ~(size_t)255;
        spec_off = (ptab_off + (size_t)n_elem * n_elem * 8 + 255) & ~(size_t)255;
        need     = spec_off + (size_t)n_nodes;
        if (need <= ws_size) break;
    }

    int nb_nodes = (n_nodes + 255) / 256;

    if (pack_ok && S >= 8) {
        unsigned long long* recs = (unsigned long long*)d_ws;
        uint16_t* partial = (uint16_t*)((char*)d_ws + part_off);
        float2*   ptab    = (float2*)((char*)d_ws + ptab_off);
        uint8_t*  spec    = (uint8_t*)((char*)d_ws + spec_off);

        species_kernel<<<nb_nodes, 256, 0, stream>>>(
            node_attrs, spec, n_nodes, n_elem);
        pair_kernel<<<1, PT_MAX, 0, stream>>>(atomic_numbers, ptab, n_elem);
        int nb_energy = TOTAL / 1024;     // TOTAL mult of 4096
        energy_pack_kernel<<<nb_energy, 256, 0, stream>>>(
            lengths, src, dst, spec, ptab, rmax_ptr, recs,
            n_edges, TOTAL, n_elem, nb, qshift, vec_ok);
        accum_kernel<<<P * S, 512, 0, stream>>>(
            recs, partial, S, EPB, npad, nb, qshift);
        combine_kernel<<<nb_nodes, 256, 0, stream>>>(
            partial, out, n_nodes, S, npad);
    } else {
        // fallback: replicated-atomic path (R2)
        int stride = ((n_nodes + 49) / 2) * 2;
        int R = 16;
        while (R > 1 &&
               (size_t)R * stride * sizeof(float) + (size_t)n_nodes * sizeof(float2)
                   > ws_size)
            R >>= 1;
        float2* ztab = (float2*)((char*)d_ws + (size_t)R * stride * sizeof(float));
        hipMemsetAsync(d_ws, 0, (size_t)R * stride * sizeof(float), stream);
        prep_nodes_kernel<<<nb_nodes, 256, 0, stream>>>(
            node_attrs, atomic_numbers, ztab, n_nodes, n_elem);
        zero_out_kernel<<<nb_nodes, 256, 0, stream>>>(out, n_nodes);
        int n_thread4 = (n_edges + 3) / 4;
        int nb_edges = (n_thread4 + 255) / 256;
        edge_kernel_atomic<<<nb_edges, 256, 0, stream>>>(
            lengths, src, dst, ztab, rmax_ptr, out, n_edges);
    }
}

// Round 11
// 248.175 us; speedup vs baseline: 1.8449x; 1.8449x over previous
//
#include <hip/hip_runtime.h>
#include <hip/hip_bf16.h>
#include <stdint.h>

// ---------------------------------------------------------------------------
// PairRepulsionSwitch: per-edge ZBL + r^-12 repulsion, quarter-summed to both
// endpoint nodes.
//
// R1-R9: atomics rate-limit (655us) -> binning (373) -> LDS sort (327) ->
//   multipass LDS accum (273) -> split energy/accum (252; accum 78us,
//   ~90us fixed harness overhead identified).
// R10: species trick + 8B packed records halved accum traffic (FETCH
//   109->76MB, confirmed) BUT padding records decode to node 0 -> p=0
//   blocks do ~560K serialized same-address LDS atomics -> accum 287us,
//   occupancy 13% (four pad-only slices run alone for ~280us).
// R11: clamp accum scan to n_edges (padding never decoded). Everything else
//   from R10 kept: uint8 species gathers (L1-friendly), 100-entry LDS pair
//   table, 8-rec/iter uint4 loads, S%8==0 XCD swizzle, bf16 partials.
// ---------------------------------------------------------------------------

#define KE_CONST 14.3996454784255f
constexpr float INV_AC = 1.0f / (0.88534f * 0.52917721092f);

#define NR 12800             // nodes per range (50 KB accumulator, 3 blk/CU)
#define PT_MAX 256           // max n_elem^2 pair-table entries

// ---------------------------------------------------------------- shared math
// c.x = KE*Zi*Zj*SCALE, c.y = (Zi^0.23 + Zj^0.23) * INV_AC
__device__ __forceinline__ float edge_energy_pt(float len, float2 c,
                                                float inv_rmax) {
    float r = fmaxf(len, 0.2f);                 // R_MIN clamp
    float inv_r = 1.0f / r;

    float u = fmaxf(1.0f - r * inv_rmax, 0.0f);
    float u2 = u * u;
    float pc = u2 * u2 * u2;                    // (1-x)^6

    float x = r * c.y;
    float phi = 0.1818f   * __expf(-3.2f    * x)
              + 0.5099f   * __expf(-0.9423f * x)
              + 0.2802f   * __expf(-0.4029f * x)
              + 0.02817f  * __expf(-0.2016f * x);
    float v_zbl = c.x * phi * inv_r * pc;

    float ir2 = inv_r * inv_r;
    float ir4 = ir2 * ir2;
    float ir12 = ir4 * ir4 * ir4;
    float t = fminf(fmaxf((1.5f - r) * 5.0f, 0.0f), 1.0f);
    float sm = t * t * (3.0f - 2.0f * t);
    float v_r12 = 1e-4f * ir12 * pc * sm;

    return 0.25f * (v_zbl + v_r12);
}

__device__ __forceinline__ float edge_energy(float len, float2 zi, float2 zj,
                                             float inv_rmax) {
    float2 c = make_float2(KE_CONST * zi.x * zj.x, (zi.y + zj.y) * INV_AC);
    return edge_energy_pt(len, c, inv_rmax);
}

__device__ __forceinline__ uint16_t f32_to_bf16_rne(float v) {
    uint32_t u = __float_as_uint(v);
    u += 0x7FFFu + ((u >> 16) & 1u);
    return (uint16_t)(u >> 16);
}

// ---------------------------------------------------------------- prep
__global__ void species_kernel(const float* __restrict__ node_attrs,
                               uint8_t* __restrict__ spec,
                               int n_nodes, int n_elem) {
    int i = blockIdx.x * blockDim.x + threadIdx.x;
    if (i >= n_nodes) return;
    float v = 0.0f;
    for (int k = 0; k < n_elem; ++k)
        v += node_attrs[i * n_elem + k] * (float)k;
    spec[i] = (uint8_t)(v + 0.5f);
}

__global__ void pair_kernel(const float* __restrict__ atomic_numbers,
                            float2* __restrict__ ptab, int n_elem) {
    int idx = threadIdx.x;
    int n2 = n_elem * n_elem;
    if (idx >= n2) return;
    int i = idx / n_elem, j = idx % n_elem;
    float Zi = atomic_numbers[i], Zj = atomic_numbers[j];
    ptab[idx] = make_float2(KE_CONST * Zi * Zj,
                            (powf(Zi, 0.23f) + powf(Zj, 0.23f)) * INV_AC);
}

__global__ void prep_nodes_kernel(const float* __restrict__ node_attrs,
                                  const float* __restrict__ atomic_numbers,
                                  float2* __restrict__ ztab,
                                  int n_nodes, int n_elem) {
    int i = blockIdx.x * blockDim.x + threadIdx.x;
    if (i >= n_nodes) return;
    float z = 0.0f;
    for (int k = 0; k < n_elem; ++k)
        z += node_attrs[i * n_elem + k] * atomic_numbers[k];
    ztab[i] = make_float2(z, powf(z, 0.23f));
}

// ------------------------------------------------- energy + pack (8B records)
__global__ __launch_bounds__(256) void energy_pack_kernel(
    const float* __restrict__ lengths,
    const int* __restrict__ src, const int* __restrict__ dst,
    const uint8_t* __restrict__ spec,
    const float2* __restrict__ ptab_g,
    const float* __restrict__ rmax_ptr,
    unsigned long long* __restrict__ recs,
    int n_edges, int total, int n_elem, int nb, int qshift, int vec_ok) {
    __shared__ float2 pt[PT_MAX];
    int tid = threadIdx.x;
    int n2 = n_elem * n_elem;
    for (int i = tid; i < n2; i += 256) pt[i] = ptab_g[i];
    __syncthreads();

    const float inv_rmax = 1.0f / rmax_ptr[0];
    int t = blockIdx.x * blockDim.x + tid;
    int base = t * 4;
    if (base >= total) return;
    int nb2 = 2 * nb;

    if (vec_ok && base + 3 < n_edges) {
        float4 L  = *reinterpret_cast<const float4*>(lengths + base);
        int4   S4 = *reinterpret_cast<const int4*>(src + base);
        int4   D4 = *reinterpret_cast<const int4*>(dst + base);
        int sv[4] = {S4.x, S4.y, S4.z, S4.w};
        int dv[4] = {D4.x, D4.y, D4.z, D4.w};
        float lv[4] = {L.x, L.y, L.z, L.w};
        int spi[4], spj[4];
#pragma unroll
        for (int k = 0; k < 4; ++k) {
            spi[k] = spec[sv[k]];
            spj[k] = spec[dv[k]];
        }
        unsigned long long rv[4];
#pragma unroll
        for (int k = 0; k < 4; ++k) {
            float2 c = pt[spi[k] * n_elem + spj[k]];
            float q = edge_energy_pt(lv[k], c, inv_rmax);
            uint32_t qu = __float_as_uint(q) >> qshift;
            rv[k] = (unsigned long long)(unsigned)sv[k]
                  | ((unsigned long long)(unsigned)dv[k] << nb)
                  | ((unsigned long long)qu << nb2);
        }
        uint4* out = reinterpret_cast<uint4*>(recs + base);
        out[0] = make_uint4((uint32_t)rv[0], (uint32_t)(rv[0] >> 32),
                            (uint32_t)rv[1], (uint32_t)(rv[1] >> 32));
        out[1] = make_uint4((uint32_t)rv[2], (uint32_t)(rv[2] >> 32),
                            (uint32_t)rv[3], (uint32_t)(rv[3] >> 32));
    } else {
        for (int k = 0; k < 4; ++k) {
            int e = base + k;
            if (e >= total) break;
            unsigned long long rec = 0ull;
            if (e < n_edges) {
                int si = src[e], di = dst[e];
                float2 c = pt[spec[si] * n_elem + spec[di]];
                float q = edge_energy_pt(lengths[e], c, inv_rmax);
                uint32_t qu = __float_as_uint(q) >> qshift;
                rec = (unsigned long long)(unsigned)si
                    | ((unsigned long long)(unsigned)di << nb)
                    | ((unsigned long long)qu << (2 * nb));
            }
            recs[e] = rec;
        }
    }
}

// --------------------------------------------------------------- accumulate
__device__ __forceinline__ void accum_rec(
    unsigned long long rec, float* __restrict__ acc,
    unsigned base, unsigned nmask, int nb, int nb2, int qshift) {
    unsigned sn = (unsigned)rec & nmask;
    unsigned dn = (unsigned)(rec >> nb) & nmask;
    float q = __uint_as_float((uint32_t)(rec >> nb2) << qshift);
    unsigned a = sn - base;
    if (a < NR) atomicAdd(&acc[a], q);
    unsigned b = dn - base;
    if (b < NR) atomicAdd(&acc[b], q);
}

__global__ __launch_bounds__(512) void accum_kernel(
    const unsigned long long* __restrict__ recs,
    uint16_t* __restrict__ partial,      // S rows of npad bf16
    int n_edges, int S, int EPB, int npad, int nb, int qshift) {
    __shared__ float acc[NR];
    int tid = threadIdx.x;
    for (int i = tid; i < NR; i += 512) acc[i] = 0.0f;
    __syncthreads();

    int s = blockIdx.x % S;              // S%8==0: same-s blocks -> same XCD
    int p = blockIdx.x / S;
    const unsigned base = (unsigned)p * NR;
    const unsigned nmask = (1u << nb) - 1u;
    const int nb2 = 2 * nb;

    int e0 = s * EPB;
    // CLAMP to n_edges: padding records decode to node 0 and would serialize
    // on acc[0] for p==0 (the R10 bug: 4 pad-only slices ran 286us alone).
    int e1 = min(e0 + EPB, n_edges);

    for (int off = e0 + tid * 8; off < e1; off += 512 * 8) {
        if (off + 8 <= e1) {
            uint4 r0 = *reinterpret_cast<const uint4*>(recs + off);
            uint4 r1 = *reinterpret_cast<const uint4*>(recs + off + 2);
            uint4 r2 = *reinterpret_cast<const uint4*>(recs + off + 4);
            uint4 r3 = *reinterpret_cast<const uint4*>(recs + off + 6);
            uint4 rr[4] = {r0, r1, r2, r3};
#pragma unroll
            for (int k = 0; k < 4; ++k) {
                unsigned long long ra = (unsigned long long)rr[k].x
                                      | ((unsigned long long)rr[k].y << 32);
                unsigned long long rb = (unsigned long long)rr[k].z
                                      | ((unsigned long long)rr[k].w << 32);
                accum_rec(ra, acc, base, nmask, nb, nb2, qshift);
                accum_rec(rb, acc, base, nmask, nb, nb2, qshift);
            }
        } else {
            for (int e = off; e < e1; ++e)
                accum_rec(recs[e], acc, base, nmask, nb, nb2, qshift);
        }
    }
    __syncthreads();

    uint16_t* __restrict__ row = partial + (size_t)s * npad + base;
    for (int i = tid; i < NR; i += 512)
        row[i] = f32_to_bf16_rne(acc[i]);
}

__global__ void combine_kernel(const uint16_t* __restrict__ partial,
                               float* __restrict__ out,
                               int n_nodes, int S, int npad) {
    int i = blockIdx.x * blockDim.x + threadIdx.x;
    if (i >= n_nodes) return;
    float t = 0.0f;
    for (int s = 0; s < S; ++s) {
        uint32_t h = partial[(size_t)s * npad + i];
        t += __uint_as_float(h << 16);
    }
    out[i] = t;
}

// ----------------------------------------------------------- fallback (R2)
__global__ void zero_out_kernel(float* __restrict__ out, int n) {
    int i = blockIdx.x * blockDim.x + threadIdx.x;
    if (i < n) out[i] = 0.0f;
}

__global__ __launch_bounds__(256) void edge_kernel_atomic(
    const float* __restrict__ lengths,
    const int* __restrict__ src_idx,
    const int* __restrict__ dst_idx,
    const float2* __restrict__ ztab,
    const float* __restrict__ rmax_ptr,
    float* __restrict__ out,
    int n_edges) {
    const float inv_rmax = 1.0f / rmax_ptr[0];
    int t = blockIdx.x * blockDim.x + threadIdx.x;
    int base = t * 4;
    if (base + 3 < n_edges) {
        float4 L = *reinterpret_cast<const float4*>(lengths + base);
        int4 S = *reinterpret_cast<const int4*>(src_idx + base);
        int4 D = *reinterpret_cast<const int4*>(dst_idx + base);
        float l[4] = {L.x, L.y, L.z, L.w};
        int s[4] = {S.x, S.y, S.z, S.w};
        int d[4] = {D.x, D.y, D.z, D.w};
        float2 zs[4], zd[4];
#pragma unroll
        for (int k = 0; k < 4; ++k) { zs[k] = ztab[s[k]]; zd[k] = ztab[d[k]]; }
#pragma unroll
        for (int k = 0; k < 4; ++k) {
            float q = edge_energy(l[k], zs[k], zd[k], inv_rmax);
            unsafeAtomicAdd(&out[s[k]], q);
            unsafeAtomicAdd(&out[d[k]], q);
        }
    } else if (base < n_edges) {
        for (int e = base; e < n_edges; ++e) {
            int si = src_idx[e], di = dst_idx[e];
            float q = edge_energy(lengths[e], ztab[si], ztab[di], inv_rmax);
            unsafeAtomicAdd(&out[si], q);
            unsafeAtomicAdd(&out[di], q);
        }
    }
}

// ---------------------------------------------------------------- launcher
extern "C" void kernel_launch(void* const* d_in, const int* in_sizes, int n_in,
                              void* d_out, int out_size, void* d_ws, size_t ws_size,
                              hipStream_t stream) {
    const float* lengths        = (const float*)d_in[0];
    const float* node_attrs     = (const float*)d_in[1];
    const int*   edge_index     = (const int*)d_in[2];
    const float* atomic_numbers = (const float*)d_in[3];
    const float* rmax_ptr       = (const float*)d_in[4];

    int n_edges = in_sizes[0];
    int n_elem  = in_sizes[3];
    int n_nodes = out_size;
    float* out = (float*)d_out;

    const int* src = edge_index;
    const int* dst = edge_index + n_edges;

    int P    = (n_nodes + NR - 1) / NR;
    int npad = P * NR;
    int vec_ok = ((n_edges & 3) == 0) ? 1 : 0;

    // record packing: nb bits per node id, q gets 64-2nb (<=32) bits
    int nb = 1;
    while ((1u << nb) < (unsigned)n_nodes) nb++;
    int qb = 64 - 2 * nb;
    if (qb > 32) qb = 32;
    int qshift = 32 - qb;
    bool pack_ok = (2 * nb + 16 <= 64) && (n_elem * n_elem <= PT_MAX);

    // S: multiple of 8 (XCD invariant), grid P*S <= 768 (3 blk/CU, 50KB LDS)
    int S = (768 / P) & ~7;
    if (S < 8) S = 8;
    size_t part_off = 0, ptab_off = 0, spec_off = 0, need = 0;
    int EPB = 0, TOTAL = 0;
    for (; S >= 8; S -= 8) {
        EPB = (((n_edges + S - 1) / S) + 4095) & ~4095;   // mult of 4096
        TOTAL = S * EPB;
        part_off = ((size_t)TOTAL * 8 + 255) & ~(size_t)255;
        ptab_off = (part_off + (size_t)S * npad * 2 + 255) & ~(size_t)255;
        spec_off = (ptab_off + (size_t)n_elem * n_elem * 8 + 255) & ~(size_t)255;
        need     = spec_off + (size_t)n_nodes;
        if (need <= ws_size) break;
    }

    int nb_nodes = (n_nodes + 255) / 256;

    if (pack_ok && S >= 8) {
        unsigned long long* recs = (unsigned long long*)d_ws;
        uint16_t* partial = (uint16_t*)((char*)d_ws + part_off);
        float2*   ptab    = (float2*)((char*)d_ws + ptab_off);
        uint8_t*  spec    = (uint8_t*)((char*)d_ws + spec_off);

        species_kernel<<<nb_nodes, 256, 0, stream>>>(
            node_attrs, spec, n_nodes, n_elem);
        pair_kernel<<<1, PT_MAX, 0, stream>>>(atomic_numbers, ptab, n_elem);
        int nb_energy = TOTAL / 1024;     // TOTAL mult of 4096
        energy_pack_kernel<<<nb_energy, 256, 0, stream>>>(
            lengths, src, dst, spec, ptab, rmax_ptr, recs,
            n_edges, TOTAL, n_elem, nb, qshift, vec_ok);
        accum_kernel<<<P * S, 512, 0, stream>>>(
            recs, partial, n_edges, S, EPB, npad, nb, qshift);
        combine_kernel<<<nb_nodes, 256, 0, stream>>>(
            partial, out, n_nodes, S, npad);
    } else {
        // fallback: replicated-atomic path (R2)
        int stride = ((n_nodes + 49) / 2) * 2;
        int R = 16;
        while (R > 1 &&
               (size_t)R * stride * sizeof(float) + (size_t)n_nodes * sizeof(float2)
                   > ws_size)
            R >>= 1;
        float2* ztab = (float2*)((char*)d_ws + (size_t)R * stride * sizeof(float));
        hipMemsetAsync(d_ws, 0, (size_t)R * stride * sizeof(float), stream);
        prep_nodes_kernel<<<nb_nodes, 256, 0, stream>>>(
            node_attrs, atomic_numbers, ztab, n_nodes, n_elem);
        zero_out_kernel<<<nb_nodes, 256, 0, stream>>>(out, n_nodes);
        int n_thread4 = (n_edges + 3) / 4;
        int nb_edges = (n_thread4 + 255) / 256;
        edge_kernel_atomic<<<nb_edges, 256, 0, stream>>>(
            lengths, src, dst, ztab, rmax_ptr, out, n_edges);
    }
}